// Round 7
// baseline (542.983 us; speedup 1.0000x reference)
//
#include <hip/hip_runtime.h>
#include <math.h>

#define NTOK 131072
#define EMB  2048
#define UDIM 128
#define KDIM 2176   // EMB + UDIM
#define NE   64
#define TOPK 8

#define BM     128   // tokens per block (8 waves x 16 tokens)
#define BK     64    // K chunk (2 MFMA K-steps)
#define NCHUNK 34    // KDIM / BK
#define NKSTEP 68    // KDIM / 32
#define LSTR   65    // f32 logits row stride in LDS
#define MARGIN 1e-4f // rank-8/9 gap below which we recompute in f64
#define WPLANE ((size_t)NKSTEP * 64 * 32)   // bf16 elems per W plane

typedef short bf16x8 __attribute__((ext_vector_type(8)));
typedef float f32x4  __attribute__((ext_vector_type(4)));

union FragU { uint4 u; bf16x8 v; };

__device__ __forceinline__ unsigned rnbf(unsigned u) {
    // round-to-nearest-even f32 -> bf16 (result in top 16 bits)
    return u + 0x7FFFu + ((u >> 16) & 1u);
}

// 8 f32 -> packed bf16 hi plane + lo plane (proven RNE split, round 3)
__device__ __forceinline__ void cvt8(const float4 a, const float4 b,
                                     uint4& hi, uint4& lo) {
    const float x[8] = {a.x, a.y, a.z, a.w, b.x, b.y, b.z, b.w};
    unsigned hh[4], ll[4];
    #pragma unroll
    for (int p = 0; p < 4; ++p) {
        const unsigned u0 = __float_as_uint(x[2*p]);
        const unsigned u1 = __float_as_uint(x[2*p+1]);
        const unsigned r0 = rnbf(u0), r1 = rnbf(u1);
        hh[p] = (r0 >> 16) | (r1 & 0xFFFF0000u);
        const float h0 = __uint_as_float(r0 & 0xFFFF0000u);
        const float h1 = __uint_as_float(r1 & 0xFFFF0000u);
        const unsigned s0 = rnbf(__float_as_uint(x[2*p]   - h0));
        const unsigned s1 = rnbf(__float_as_uint(x[2*p+1] - h1));
        ll[p] = (s0 >> 16) | (s1 & 0xFFFF0000u);
    }
    hi = make_uint4(hh[0], hh[1], hh[2], hh[3]);
    lo = make_uint4(ll[0], ll[1], ll[2], ll[3]);
}

// W f32 -> bf16 hi/lo planes in per-lane fragment order:
// wh[(ks*64 + e)*32 + lk*8 + j] = bf16(W[e][ks*32 + lk*8 + j])
__global__ __launch_bounds__(256)
void prep_w(const float* __restrict__ W,
            unsigned short* __restrict__ wh,
            unsigned short* __restrict__ wl)
{
    const int t = blockIdx.x * 256 + threadIdx.x;   // [0, 68*64*4)
    if (t >= NKSTEP * 64 * 4) return;
    const int lk = t & 3, e = (t >> 2) & 63, ks = t >> 8;
    const float* p = W + (size_t)e * KDIM + ks * 32 + lk * 8;
    const float4 a = *reinterpret_cast<const float4*>(p);
    const float4 c = *reinterpret_cast<const float4*>(p + 4);
    uint4 hi, lo;
    cvt8(a, c, hi, lo);
    const size_t di = ((size_t)ks * 64 + e) * 32 + lk * 8;
    *reinterpret_cast<uint4*>(wh + di) = hi;
    *reinterpret_cast<uint4*>(wl + di) = lo;
}

__global__ void zero_flags(int* flagbuf) {
    if (threadIdx.x == 0 && blockIdx.x == 0) flagbuf[0] = 0;
}

__global__ __launch_bounds__(512, 4)
void gate_main(const float* __restrict__ h,
               const float* __restrict__ u,
               const unsigned short* __restrict__ wh,
               const unsigned short* __restrict__ wl,
               const float* __restrict__ b,
               int* __restrict__ flagbuf,
               float* __restrict__ out)
{
    __shared__ __align__(16) float ls[BM * LSTR];   // 33280 B
    __shared__ int flaglist[BM];
    __shared__ int nflag;

    const int tid  = threadIdx.x;
    const int lane = tid & 63;
    const int wid  = tid >> 6;    // 8 waves, 16 tokens each
    const int bm   = blockIdx.x * BM;
    const int lrow = lane & 15;   // fragment row/col
    const int lk   = lane >> 4;   // fragment k-quarter

    if (tid == 0) nflag = 0;

    f32x4 acc[4];
    #pragma unroll
    for (int ni = 0; ni < 4; ++ni)
        acc[ni] = (f32x4){0.f, 0.f, 0.f, 0.f};

    auto loadX = [&](int c, float4 xr[4]) {
        const bool  fh  = (c < 32);
        const float* src = fh ? h : u;
        const int   ld  = fh ? EMB : UDIM;
        const int   kb  = c * BK - (fh ? 0 : EMB);
        const size_t ro = (size_t)(bm + wid*16 + lrow) * ld + kb + lk*8;
        xr[0] = *reinterpret_cast<const float4*>(src + ro);
        xr[1] = *reinterpret_cast<const float4*>(src + ro + 4);
        xr[2] = *reinterpret_cast<const float4*>(src + ro + 32);
        xr[3] = *reinterpret_cast<const float4*>(src + ro + 36);
    };

    auto compute = [&](const float4 xr[4], int c) {
        #pragma unroll
        for (int s = 0; s < 2; ++s) {
            const int ks = c*2 + s;
            const uint4* bH = reinterpret_cast<const uint4*>(wh + (size_t)ks * 2048);
            const uint4* bL = reinterpret_cast<const uint4*>(wl + (size_t)ks * 2048);
            FragU bh[4], bl[4];
            #pragma unroll
            for (int ni = 0; ni < 4; ++ni) {
                const int off = (ni*16 + lrow)*4 + lk;
                bh[ni].u = bH[off];
                bl[ni].u = bL[off];
            }
            FragU ah, al;
            cvt8(xr[s*2], xr[s*2 + 1], ah.u, al.u);
            #pragma unroll
            for (int ni = 0; ni < 4; ++ni) {
                acc[ni] = __builtin_amdgcn_mfma_f32_16x16x32_bf16(ah.v, bh[ni].v, acc[ni], 0, 0, 0);
                acc[ni] = __builtin_amdgcn_mfma_f32_16x16x32_bf16(ah.v, bl[ni].v, acc[ni], 0, 0, 0);
                acc[ni] = __builtin_amdgcn_mfma_f32_16x16x32_bf16(al.v, bh[ni].v, acc[ni], 0, 0, 0);
            }
        }
    };

    // ---- barrier-free ping-pong K loop (counted vmcnt by construction) ----
    float4 xA[4], xB[4];
    loadX(0, xA);
    loadX(1, xB);
    for (int c = 0; c < 32; c += 2) {
        compute(xA, c);          // waits only for A's loads; B stays in flight
        loadX(c + 2, xA);
        compute(xB, c + 1);      // waits only for B's; A(c+2) stays in flight
        loadX(c + 3, xB);
    }
    compute(xA, 32);
    compute(xB, 33);

    // ---- C-write: logits + bias into f32 LDS ----
    #pragma unroll
    for (int ni = 0; ni < 4; ++ni) {
        const float be = b[ni*16 + lrow];
        #pragma unroll
        for (int r = 0; r < 4; ++r) {
            const int tl = wid*16 + lk*4 + r;
            ls[tl * LSTR + ni*16 + lrow] = acc[ni][r] + be;
        }
    }
    __syncthreads();

    // ---- per-token top-8 + margin + softmax (1 thread : 1 token) ----
    if (tid < BM) {
        float* row = ls + tid * LSTR;
        unsigned long long selm = 0ULL;
        float mx = 0.f, l8 = 0.f, l9 = 0.f;
        for (int s = 0; s < TOPK + 1; ++s) {
            float best = -1e30f; int bi = 0;
            #pragma unroll
            for (int e = 0; e < NE; ++e) {
                const float v = row[e];
                if (!((selm >> e) & 1ULL) && v > best) { best = v; bi = e; }
            }
            if (s == 0) mx = best;
            if (s < TOPK) selm |= 1ULL << bi;
            if (s == TOPK - 1) l8 = best;
            if (s == TOPK)     l9 = best;
        }
        if (l8 - l9 < MARGIN) {
            const int slot = atomicAdd(&nflag, 1);
            flaglist[slot] = tid;
        }
        float tot = 0.f, s8 = 0.f;
        #pragma unroll
        for (int e = 0; e < NE; ++e) {
            const float p = __expf(row[e] - mx);
            tot += p;
            if ((selm >> e) & 1ULL) s8 += p;
            row[e] = p;
        }
        const float inv = 1.f / (s8 + 1e-9f * tot);
        #pragma unroll
        for (int e = 0; e < NE; ++e)
            row[e] = ((selm >> e) & 1ULL) ? row[e] * inv : 0.f;
    }
    __syncthreads();

    // ---- coalesced float4 store (512 threads: 32 rows x 16 float4 cols) ----
    {
        const int tx = tid & 15, ty = tid >> 4;   // ty 0..31
        #pragma unroll
        for (int r = 0; r < 4; ++r) {
            const int m = ty + r * 32;
            float4 v;
            v.x = ls[m * LSTR + tx*4 + 0];
            v.y = ls[m * LSTR + tx*4 + 1];
            v.z = ls[m * LSTR + tx*4 + 2];
            v.w = ls[m * LSTR + tx*4 + 3];
            *reinterpret_cast<float4*>(out + (size_t)(bm + m) * NE + tx*4) = v;
        }
    }

    // ---- publish flagged tokens for the refine kernel (device-scope atomics) ----
    if (tid < nflag) {
        const int slot = atomicAdd(flagbuf, 1);
        flagbuf[1 + slot] = bm + flaglist[tid];
    }
}

// ---- exact f64 referee for margin-flagged tokens (reads original f32 W) ----
__global__ __launch_bounds__(256)
void gate_refine(const float* __restrict__ h,
                 const float* __restrict__ u,
                 const float* __restrict__ W,
                 const float* __restrict__ b,
                 const int* __restrict__ flagbuf,   // [0]=count, then token ids
                 float* __restrict__ out)
{
    __shared__ double dscr[576];
    const int nf = flagbuf[0];
    for (int f = blockIdx.x; f < nf; f += gridDim.x) {
        const int tok  = flagbuf[1 + f];
        const int tid  = threadIdx.x;
        const int e    = tid & 63;
        const int part = tid >> 6;          // 4 K-partitions x 544
        const int ka = part * 544, kb2 = ka + 544;
        double s = 0.0;
        #pragma unroll 4
        for (int k = ka; k < kb2; ++k) {
            const float xv = (k < EMB) ? h[(size_t)tok * EMB + k]
                                       : u[(size_t)tok * UDIM + (k - EMB)];
            s = fma((double)xv, (double)W[(size_t)e * KDIM + k], s);
        }
        dscr[part * 64 + e] = s;
        __syncthreads();
        if (tid < NE) {
            const double l = dscr[tid] + dscr[64 + tid] + dscr[128 + tid] +
                             dscr[192 + tid] + (double)b[tid];
            dscr[512 + tid] = l;
        }
        __syncthreads();
        if (tid == 0) {
            double* dl = dscr + 512;
            double mx = dl[0];
            #pragma unroll
            for (int e2 = 1; e2 < NE; ++e2) mx = fmax(mx, dl[e2]);
            double tot = 0.0;
            #pragma unroll
            for (int e2 = 0; e2 < NE; ++e2) {
                const double p = exp(dl[e2] - mx);
                dl[e2] = p;
                tot += p;
            }
            double s8 = 0.0;
            for (int ss = 0; ss < TOPK; ++ss) {
                double best = -1.0; int bi = 0;
                for (int e2 = 0; e2 < NE; ++e2) {
                    const double p = dl[e2];
                    if (p > best) { best = p; bi = e2; }
                }
                s8 += best;
                dl[bi] = -best;
            }
            const double inv = 1.0 / (s8 + 1e-9 * tot);
            for (int e2 = 0; e2 < NE; ++e2) {
                const double p = dl[e2];
                out[(size_t)tok * NE + e2] = (float)((p < 0.0) ? (-p) * inv : 0.0);
            }
        }
        __syncthreads();
    }
}

extern "C" void kernel_launch(void* const* d_in, const int* in_sizes, int n_in,
                              void* d_out, int out_size, void* d_ws, size_t ws_size,
                              hipStream_t stream) {
    const float* h = (const float*)d_in[0];
    const float* u = (const float*)d_in[1];
    const float* W = (const float*)d_in[2];
    const float* b = (const float*)d_in[3];
    float* out = (float*)d_out;
    (void)in_sizes; (void)n_in; (void)out_size; (void)ws_size;

    unsigned short* wh = (unsigned short*)d_ws;
    unsigned short* wl = wh + WPLANE;
    int* flagbuf = (int*)(wl + WPLANE);   // [0]=count, then up to NTOK ids

    hipLaunchKernelGGL(zero_flags, dim3(1), dim3(64), 0, stream, flagbuf);
    hipLaunchKernelGGL(prep_w, dim3(NKSTEP), dim3(256), 0, stream, W, wh, wl);
    hipLaunchKernelGGL(gate_main, dim3(NTOK / BM), dim3(512), 0, stream,
                       h, u, wh, wl, b, flagbuf, out);
    hipLaunchKernelGGL(gate_refine, dim3(256), dim3(256), 0, stream,
                       h, u, W, b, flagbuf, out);
}

// Round 8
// 447.490 us; speedup vs baseline: 1.2134x; 1.2134x over previous
//
#include <hip/hip_runtime.h>
#include <math.h>

#define NTOK 131072
#define EMB  2048
#define UDIM 128
#define KDIM 2176   // EMB + UDIM
#define NE   64
#define TOPK 8

#define BM     128   // tokens per block (4 waves x 32 tokens)
#define BK     64    // K chunk (2 MFMA K-steps)
#define NCHUNK 34    // KDIM / BK
#define NKSTEP 68    // KDIM / 32
#define LSTR   65    // f32 logits row stride in LDS
#define MARGIN 1e-4f // rank-8/9 gap below which we recompute in f64
#define WPLANE ((size_t)NKSTEP * 64 * 32)   // bf16 elems per W plane

typedef short bf16x8 __attribute__((ext_vector_type(8)));
typedef float f32x4  __attribute__((ext_vector_type(4)));

union FragU { uint4 u; bf16x8 v; };

__device__ __forceinline__ unsigned rnbf(unsigned u) {
    // round-to-nearest-even f32 -> bf16 (result in top 16 bits)
    return u + 0x7FFFu + ((u >> 16) & 1u);
}

// 8 f32 -> packed bf16 hi plane + lo plane (proven RNE split, round 3)
__device__ __forceinline__ void cvt8(const float4 a, const float4 b,
                                     uint4& hi, uint4& lo) {
    const float x[8] = {a.x, a.y, a.z, a.w, b.x, b.y, b.z, b.w};
    unsigned hh[4], ll[4];
    #pragma unroll
    for (int p = 0; p < 4; ++p) {
        const unsigned u0 = __float_as_uint(x[2*p]);
        const unsigned u1 = __float_as_uint(x[2*p+1]);
        const unsigned r0 = rnbf(u0), r1 = rnbf(u1);
        hh[p] = (r0 >> 16) | (r1 & 0xFFFF0000u);
        const float h0 = __uint_as_float(r0 & 0xFFFF0000u);
        const float h1 = __uint_as_float(r1 & 0xFFFF0000u);
        const unsigned s0 = rnbf(__float_as_uint(x[2*p]   - h0));
        const unsigned s1 = rnbf(__float_as_uint(x[2*p+1] - h1));
        ll[p] = (s0 >> 16) | (s1 & 0xFFFF0000u);
    }
    hi = make_uint4(hh[0], hh[1], hh[2], hh[3]);
    lo = make_uint4(ll[0], ll[1], ll[2], ll[3]);
}

// W f32 -> bf16 hi/lo planes in per-lane fragment order:
// wh[(ks*64 + e)*32 + lk*8 + j] = bf16(W[e][ks*32 + lk*8 + j])
__global__ __launch_bounds__(256)
void prep_w(const float* __restrict__ W,
            unsigned short* __restrict__ wh,
            unsigned short* __restrict__ wl)
{
    const int t = blockIdx.x * 256 + threadIdx.x;   // [0, 68*64*4)
    if (t >= NKSTEP * 64 * 4) return;
    const int lk = t & 3, e = (t >> 2) & 63, ks = t >> 8;
    const float* p = W + (size_t)e * KDIM + ks * 32 + lk * 8;
    const float4 a = *reinterpret_cast<const float4*>(p);
    const float4 c = *reinterpret_cast<const float4*>(p + 4);
    uint4 hi, lo;
    cvt8(a, c, hi, lo);
    const size_t di = ((size_t)ks * 64 + e) * 32 + lk * 8;
    *reinterpret_cast<uint4*>(wh + di) = hi;
    *reinterpret_cast<uint4*>(wl + di) = lo;
}

__global__ void zero_flags(int* flagbuf) {
    if (threadIdx.x == 0 && blockIdx.x == 0) flagbuf[0] = 0;
}

__global__ __launch_bounds__(256)
void gate_main(const float* __restrict__ h,
               const float* __restrict__ u,
               const unsigned short* __restrict__ wh,
               const unsigned short* __restrict__ wl,
               const float* __restrict__ b,
               int* __restrict__ flagbuf,
               float* __restrict__ out)
{
    __shared__ __align__(16) float ls[BM * LSTR];   // 33280 B
    __shared__ int flaglist[BM];
    __shared__ int nflag;

    const int tid  = threadIdx.x;
    const int lane = tid & 63;
    const int wid  = tid >> 6;    // 4 waves, 32 tokens each
    const int bm   = blockIdx.x * BM;
    const int lrow = lane & 15;   // fragment row/col
    const int lk   = lane >> 4;   // fragment k-quarter

    if (tid == 0) nflag = 0;

    f32x4 acc[2][4];
    #pragma unroll
    for (int mi = 0; mi < 2; ++mi)
        #pragma unroll
        for (int ni = 0; ni < 4; ++ni)
            acc[mi][ni] = (f32x4){0.f, 0.f, 0.f, 0.f};

    auto loadX = [&](int c, float4 xr[8]) {
        const bool  fh  = (c < 32);
        const float* src = fh ? h : u;
        const int   ld  = fh ? EMB : UDIM;
        const int   kb  = c * BK - (fh ? 0 : EMB);
        #pragma unroll
        for (int mi = 0; mi < 2; ++mi) {
            const size_t ro = (size_t)(bm + wid*32 + mi*16 + lrow) * ld + kb + lk*8;
            #pragma unroll
            for (int s = 0; s < 2; ++s) {
                xr[mi*4 + s*2 + 0] = *reinterpret_cast<const float4*>(src + ro + s*32);
                xr[mi*4 + s*2 + 1] = *reinterpret_cast<const float4*>(src + ro + s*32 + 4);
            }
        }
    };

    auto compute = [&](const float4 xr[8], int c) {
        #pragma unroll
        for (int s = 0; s < 2; ++s) {
            const int ks = c*2 + s;
            const uint4* bH = reinterpret_cast<const uint4*>(wh + (size_t)ks * 2048);
            const uint4* bL = reinterpret_cast<const uint4*>(wl + (size_t)ks * 2048);
            FragU bh[4], bl[4];
            #pragma unroll
            for (int ni = 0; ni < 4; ++ni) {
                const int off = (ni*16 + lrow)*4 + lk;
                bh[ni].u = bH[off];
                bl[ni].u = bL[off];
            }
            #pragma unroll
            for (int mi = 0; mi < 2; ++mi) {
                FragU ah, al;
                cvt8(xr[mi*4 + s*2], xr[mi*4 + s*2 + 1], ah.u, al.u);
                #pragma unroll
                for (int ni = 0; ni < 4; ++ni) {
                    acc[mi][ni] = __builtin_amdgcn_mfma_f32_16x16x32_bf16(ah.v, bh[ni].v, acc[mi][ni], 0, 0, 0);
                    acc[mi][ni] = __builtin_amdgcn_mfma_f32_16x16x32_bf16(ah.v, bl[ni].v, acc[mi][ni], 0, 0, 0);
                    acc[mi][ni] = __builtin_amdgcn_mfma_f32_16x16x32_bf16(al.v, bh[ni].v, acc[mi][ni], 0, 0, 0);
                }
            }
        }
    };

    // ---- barrier-free ping-pong K loop: no register copies, counted vmcnt
    //      by construction (each compute waits only on its own buffer's loads,
    //      issued two phases earlier; the other buffer stays in flight) ----
    float4 xA[8], xB[8];
    loadX(0, xA);
    loadX(1, xB);
    #pragma unroll 1
    for (int c = 0; c + 3 < NCHUNK; c += 2) {
        compute(xA, c);
        loadX(c + 2, xA);
        compute(xB, c + 1);
        loadX(c + 3, xB);
    }
    compute(xA, NCHUNK - 2);
    compute(xB, NCHUNK - 1);

    // ---- C-write: logits + bias into f32 LDS ----
    #pragma unroll
    for (int mi = 0; mi < 2; ++mi)
        #pragma unroll
        for (int ni = 0; ni < 4; ++ni) {
            const float be = b[ni*16 + lrow];
            #pragma unroll
            for (int r = 0; r < 4; ++r) {
                const int tl = wid*32 + mi*16 + lk*4 + r;
                const int e  = ni*16 + lrow;
                ls[tl * LSTR + e] = acc[mi][ni][r] + be;
            }
        }
    __syncthreads();

    // ---- per-token top-8 + margin + softmax (1 thread : 1 token) ----
    if (tid < BM) {
        float* row = ls + tid * LSTR;
        unsigned long long selm = 0ULL;
        float mx = 0.f, l8 = 0.f, l9 = 0.f;
        for (int s = 0; s < TOPK + 1; ++s) {
            float best = -1e30f; int bi = 0;
            #pragma unroll
            for (int e = 0; e < NE; ++e) {
                const float v = row[e];
                if (!((selm >> e) & 1ULL) && v > best) { best = v; bi = e; }
            }
            if (s == 0) mx = best;
            if (s < TOPK) selm |= 1ULL << bi;
            if (s == TOPK - 1) l8 = best;
            if (s == TOPK)     l9 = best;
        }
        if (l8 - l9 < MARGIN) {
            const int slot = atomicAdd(&nflag, 1);
            flaglist[slot] = tid;
        }
        float tot = 0.f, s8 = 0.f;
        #pragma unroll
        for (int e = 0; e < NE; ++e) {
            const float p = __expf(row[e] - mx);
            tot += p;
            if ((selm >> e) & 1ULL) s8 += p;
            row[e] = p;
        }
        const float inv = 1.f / (s8 + 1e-9f * tot);
        #pragma unroll
        for (int e = 0; e < NE; ++e)
            row[e] = ((selm >> e) & 1ULL) ? row[e] * inv : 0.f;
    }
    __syncthreads();

    // ---- coalesced float4 store ----
    {
        const int tx = tid & 15, ty = tid >> 4;
        #pragma unroll
        for (int r = 0; r < 8; ++r) {
            const int m = ty + r * 16;
            float4 v;
            v.x = ls[m * LSTR + tx*4 + 0];
            v.y = ls[m * LSTR + tx*4 + 1];
            v.z = ls[m * LSTR + tx*4 + 2];
            v.w = ls[m * LSTR + tx*4 + 3];
            *reinterpret_cast<float4*>(out + (size_t)(bm + m) * NE + tx*4) = v;
        }
    }

    // ---- publish flagged tokens for the refine kernel (device-scope atomics) ----
    if (tid < nflag) {
        const int slot = atomicAdd(flagbuf, 1);
        flagbuf[1 + slot] = bm + flaglist[tid];
    }
}

// ---- exact f64 referee for margin-flagged tokens (reads original f32 W) ----
__global__ __launch_bounds__(256)
void gate_refine(const float* __restrict__ h,
                 const float* __restrict__ u,
                 const float* __restrict__ W,
                 const float* __restrict__ b,
                 const int* __restrict__ flagbuf,   // [0]=count, then token ids
                 float* __restrict__ out)
{
    __shared__ double dscr[576];
    const int nf = flagbuf[0];
    for (int f = blockIdx.x; f < nf; f += gridDim.x) {
        const int tok  = flagbuf[1 + f];
        const int tid  = threadIdx.x;
        const int e    = tid & 63;
        const int part = tid >> 6;          // 4 K-partitions x 544
        const int ka = part * 544, kb2 = ka + 544;
        double s = 0.0;
        #pragma unroll 4
        for (int k = ka; k < kb2; ++k) {
            const float xv = (k < EMB) ? h[(size_t)tok * EMB + k]
                                       : u[(size_t)tok * UDIM + (k - EMB)];
            s = fma((double)xv, (double)W[(size_t)e * KDIM + k], s);
        }
        dscr[part * 64 + e] = s;
        __syncthreads();
        if (tid < NE) {
            const double l = dscr[tid] + dscr[64 + tid] + dscr[128 + tid] +
                             dscr[192 + tid] + (double)b[tid];
            dscr[512 + tid] = l;
        }
        __syncthreads();
        if (tid == 0) {
            double* dl = dscr + 512;
            double mx = dl[0];
            #pragma unroll
            for (int e2 = 1; e2 < NE; ++e2) mx = fmax(mx, dl[e2]);
            double tot = 0.0;
            #pragma unroll
            for (int e2 = 0; e2 < NE; ++e2) {
                const double p = exp(dl[e2] - mx);
                dl[e2] = p;
                tot += p;
            }
            double s8 = 0.0;
            for (int ss = 0; ss < TOPK; ++ss) {
                double best = -1.0; int bi = 0;
                for (int e2 = 0; e2 < NE; ++e2) {
                    const double p = dl[e2];
                    if (p > best) { best = p; bi = e2; }
                }
                s8 += best;
                dl[bi] = -best;
            }
            const double inv = 1.0 / (s8 + 1e-9 * tot);
            for (int e2 = 0; e2 < NE; ++e2) {
                const double p = dl[e2];
                out[(size_t)tok * NE + e2] = (float)((p < 0.0) ? (-p) * inv : 0.0);
            }
        }
        __syncthreads();
    }
}

extern "C" void kernel_launch(void* const* d_in, const int* in_sizes, int n_in,
                              void* d_out, int out_size, void* d_ws, size_t ws_size,
                              hipStream_t stream) {
    const float* h = (const float*)d_in[0];
    const float* u = (const float*)d_in[1];
    const float* W = (const float*)d_in[2];
    const float* b = (const float*)d_in[3];
    float* out = (float*)d_out;
    (void)in_sizes; (void)n_in; (void)out_size; (void)ws_size;

    unsigned short* wh = (unsigned short*)d_ws;
    unsigned short* wl = wh + WPLANE;
    int* flagbuf = (int*)(wl + WPLANE);   // [0]=count, then up to NTOK ids

    hipLaunchKernelGGL(zero_flags, dim3(1), dim3(64), 0, stream, flagbuf);
    hipLaunchKernelGGL(prep_w, dim3(NKSTEP), dim3(256), 0, stream, W, wh, wl);
    hipLaunchKernelGGL(gate_main, dim3(NTOK / BM), dim3(256), 0, stream,
                       h, u, wh, wl, b, flagbuf, out);
    hipLaunchKernelGGL(gate_refine, dim3(256), dim3(256), 0, stream,
                       h, u, W, b, flagbuf, out);
}